// Round 3
// baseline (432.476 us; speedup 1.0000x reference)
//
#include <hip/hip_runtime.h>

#define NTOK 49
#define CH   128
#define NHEAD 4
#define SCALE 0.17677669529663687f   // 32^-0.5

typedef __bf16 bf16x8 __attribute__((ext_vector_type(8)));
typedef short  s16x8  __attribute__((ext_vector_type(8)));
typedef float  f32x4  __attribute__((ext_vector_type(4)));

__device__ __forceinline__ unsigned short f2bf(float f) {
  unsigned int u = __builtin_bit_cast(unsigned int, f);
  u += 0x7FFFu + ((u >> 16) & 1u);          // RNE
  return (unsigned short)(u >> 16);
}

__device__ __forceinline__ f32x4 mfma_bf16(s16x8 a, s16x8 b, f32x4 c) {
  return __builtin_amdgcn_mfma_f32_16x16x32_bf16(
      __builtin_bit_cast(bf16x8, a), __builtin_bit_cast(bf16x8, b), c, 0, 0, 0);
}

// ---------------- prep: weights -> bf16 transposed (coalesced reads), rpb expand ----------------
// ws layout: wT bf16[384][128] @0 ; pT bf16[128][128] @98304B ; rpb f32[4][49*49] @131072B
__global__ void prep_kernel(const float* __restrict__ qkv_w,
                            const float* __restrict__ proj_w,
                            const float* __restrict__ bias_table,
                            unsigned short* __restrict__ wT,
                            unsigned short* __restrict__ pT,
                            float* __restrict__ rpb) {
  int t = blockIdx.x * 256 + threadIdx.x;
  if (t < 384 * 128) {
    int k = t / 384, n = t % 384;            // qkv_w is [k=128][n=384]; linear scan = coalesced
    float v = qkv_w[t];
    if (n < 128) v *= SCALE;                 // fold q scale into Wq
    wT[n * 128 + k] = f2bf(v);
  } else if (t < 384 * 128 + 128 * 128) {
    int u = t - 384 * 128;
    int k = u >> 7, n = u & 127;
    pT[n * 128 + k] = f2bf(proj_w[u]);
  } else if (t < 384 * 128 + 128 * 128 + NHEAD * NTOK * NTOK) {
    int u = t - (384 * 128 + 128 * 128);
    int h = u / (NTOK * NTOK);
    int ij = u % (NTOK * NTOK);
    int i = ij / NTOK, j = ij % NTOK;
    int idx = (i / 7 - j / 7 + 6) * 13 + (i % 7 - j % 7 + 6);
    rpb[h * (NTOK * NTOK) + ij] = bias_table[idx * NHEAD + h];
  }
}

// ---------------- fused attention: 1 window / 8-wave block; wave (mh,h) = token-half x head ----
// LDS (53760 B), heavily aliased:
//   QK  [0,36864):      per head h: q[64][36] @h*9216, k[64][36] @h*9216+4608 (bytes)
//                       P[64][72] aliases q+k per head (after barrier 3)
//                       AO bf16[64][136] aliases bytes [0,17408) (after barrier 3b)
//   VT  [36864,53760):  per head vT[32][66]
//   stage f32[49][132] @17408 (aliases dead P heads 1-3 tail + VT, after barrier 4)
// A-fragments (x) load direct from global fp32 (no staging tile).
// Occupancy: 3 blocks/CU (157.5 KB < 160 KB LDS) = 24 waves/CU = 75%.
__global__ __launch_bounds__(512, 6)
void attn_fused_kernel(const float* __restrict__ x,
                       const float* __restrict__ qkv_b,
                       const float* __restrict__ proj_b,
                       const float* __restrict__ mask,
                       const unsigned short* __restrict__ wT,
                       const unsigned short* __restrict__ pT,
                       const float* __restrict__ rpb,
                       float* __restrict__ out) {
  __shared__ __align__(16) char smem_raw[53760];
  unsigned short* const QK  = (unsigned short*)smem_raw;
  unsigned short* const VTb = (unsigned short*)(smem_raw + 36864);
  float* const stage        = (float*)(smem_raw + 17408);   // [49][132] f32

  const int w    = blockIdx.x;
  const int tid  = threadIdx.x;
  const int wv   = tid >> 6;
  const int h    = wv & 3;          // head
  const int mh   = wv >> 2;         // token half: rows [mh*32, mh*32+32)
  const int lane = tid & 63;
  const int quad = lane >> 4;
  const int l16  = lane & 15;
  const int rowbase = mh * 32;

  unsigned short* const qs = QK + h * 4608;   // q [64][36]
  unsigned short* const ks = qs + 2304;       // k [64][36]
  unsigned short* const ps = QK + h * 4608;   // P [64][72] (aliases q+k after barrier 3)
  unsigned short* const vt = VTb + h * 2112;  // vT [32][66] (d-major, token minor)

  const f32x4 fzero = {0.f, 0.f, 0.f, 0.f};
  const float* xw = x + (size_t)w * (NTOK * CH);

  // ---- A fragments: direct global fp32 loads -> bf16 (rows >=49 clamped; masked later) ----
  s16x8 af[2][4];
#pragma unroll
  for (int mt = 0; mt < 2; ++mt) {
    const int row = rowbase + mt * 16 + l16;
    const float* xr = xw + (row < NTOK ? row : NTOK - 1) * CH;
#pragma unroll
    for (int kt = 0; kt < 4; ++kt) {
      const float4 f0 = *(const float4*)(xr + kt * 32 + quad * 8);
      const float4 f1 = *(const float4*)(xr + kt * 32 + quad * 8 + 4);
      s16x8 v;
      v[0] = (short)f2bf(f0.x); v[1] = (short)f2bf(f0.y);
      v[2] = (short)f2bf(f0.z); v[3] = (short)f2bf(f0.w);
      v[4] = (short)f2bf(f1.x); v[5] = (short)f2bf(f1.y);
      v[6] = (short)f2bf(f1.z); v[7] = (short)f2bf(f1.w);
      af[mt][kt] = v;
    }
  }

  // ---- QKV GEMM (p-outer keeps acc pressure low): rows [rowbase,+32), head h ----
#pragma unroll
  for (int p = 0; p < 3; ++p) {
    f32x4 acc[2][2];
#pragma unroll
    for (int mt = 0; mt < 2; ++mt)
#pragma unroll
      for (int nt = 0; nt < 2; ++nt) acc[mt][nt] = fzero;
#pragma unroll
    for (int kt = 0; kt < 4; ++kt) {
      s16x8 b[2];
#pragma unroll
      for (int nt = 0; nt < 2; ++nt)
        b[nt] = *(const s16x8*)(wT + (size_t)(p * 128 + h * 32 + nt * 16 + l16) * 128 +
                                kt * 32 + quad * 8);
#pragma unroll
      for (int mt = 0; mt < 2; ++mt)
#pragma unroll
        for (int nt = 0; nt < 2; ++nt)
          acc[mt][nt] = mfma_bf16(af[mt][kt], b[nt], acc[mt][nt]);
    }
#pragma unroll
    for (int nt = 0; nt < 2; ++nt) {
      const int col = nt * 16 + l16;               // d within head, 0..31
      float bias = qkv_b[p * 128 + h * 32 + col];
      if (p == 0) bias *= SCALE;                   // Wq pre-scaled; match bias
#pragma unroll
      for (int mt = 0; mt < 2; ++mt)
#pragma unroll
        for (int r = 0; r < 4; ++r) {
          const int row = rowbase + mt * 16 + quad * 4 + r;   // token
          const unsigned short bv = f2bf(acc[mt][nt][r] + bias);
          if (p == 0)      qs[row * 36 + col] = bv;
          else if (p == 1) ks[row * 36 + col] = bv;
          else             vt[col * 66 + row] = bv;
        }
    }
  }
  __syncthreads();   // (2) q/k/vT ready (k + vT shared within head pair)

  // ---- S = q k^T : rows [rowbase,+32) x all 64 cols (K=d=32, one MFMA per tile) ----
  s16x8 qf[2], kf[4];
#pragma unroll
  for (int mt = 0; mt < 2; ++mt)
    qf[mt] = *(const s16x8*)(qs + (rowbase + mt * 16 + l16) * 36 + quad * 8);
#pragma unroll
  for (int nt = 0; nt < 4; ++nt)
    kf[nt] = *(const s16x8*)(ks + (nt * 16 + l16) * 36 + quad * 8);
  f32x4 s[2][4];
#pragma unroll
  for (int mt = 0; mt < 2; ++mt)
#pragma unroll
    for (int nt = 0; nt < 4; ++nt)
      s[mt][nt] = mfma_bf16(qf[mt], kf[nt], fzero);
  __syncthreads();   // (3) all q/k LDS reads done before P overwrites the region

  // ---- softmax numerator: logits tiny (|S|<~3, mask in {0,-100}) -> skip max shift.
  //      exp(-1e30)=0 handles padding; row sums via MFMA-with-ones below. ----
  const float* maskw = mask + (size_t)(w & 63) * (NTOK * NTOK);
  const float* rpbh  = rpb + h * (NTOK * NTOK);
#pragma unroll
  for (int mt = 0; mt < 2; ++mt)
#pragma unroll
    for (int r = 0; r < 4; ++r) {
      const int i = rowbase + mt * 16 + quad * 4 + r;
#pragma unroll
      for (int nt = 0; nt < 4; ++nt) {
        const int j = nt * 16 + l16;
        float v = -1e30f;
        if (i < NTOK && j < NTOK) {
          const int ij = i * NTOK + j;
          v = s[mt][nt][r] + rpbh[ij] + maskw[ij];
        }
        ps[i * 72 + j] = f2bf(__expf(v));
      }
    }

  // ---- load P/V fragments, then barrier: AO (below) aliases other heads' P regions ----
  s16x8 pf[2][2], vf[2][2], ones;
#pragma unroll
  for (int e = 0; e < 8; ++e) ones[e] = (short)0x3F80;   // bf16 1.0
#pragma unroll
  for (int mt = 0; mt < 2; ++mt)
#pragma unroll
    for (int kt = 0; kt < 2; ++kt)
      pf[mt][kt] = *(const s16x8*)(ps + (rowbase + mt * 16 + l16) * 72 + kt * 32 + quad * 8);
#pragma unroll
  for (int nt = 0; nt < 2; ++nt)
#pragma unroll
    for (int kt = 0; kt < 2; ++kt)
      vf[nt][kt] = *(const s16x8*)(vt + (nt * 16 + l16) * 66 + kt * 32 + quad * 8);
  __syncthreads();   // (3b) all P/V fragment reads done before AO overwrites P of heads 0/1

  // ---- O = P v (M=32, N=32, K=64) + row-sums via MFMA with all-ones B ----
  f32x4 o[2][2], rs[2];
#pragma unroll
  for (int mt = 0; mt < 2; ++mt) {
    rs[mt] = fzero;
#pragma unroll
    for (int nt = 0; nt < 2; ++nt) o[mt][nt] = fzero;
  }
#pragma unroll
  for (int kt = 0; kt < 2; ++kt)
#pragma unroll
    for (int mt = 0; mt < 2; ++mt) {
      rs[mt] = mfma_bf16(pf[mt][kt], ones, rs[mt]);      // rowsum, C rows match o rows
#pragma unroll
      for (int nt = 0; nt < 2; ++nt)
        o[mt][nt] = mfma_bf16(pf[mt][kt], vf[nt][kt], o[mt][nt]);
    }

  // ---- AO (normalized, bf16) -> LDS [64][136] @0 ----
  unsigned short* const ao = QK;
#pragma unroll
  for (int mt = 0; mt < 2; ++mt)
#pragma unroll
    for (int r = 0; r < 4; ++r) {
      const float rsv  = rs[mt][r];
      const float rinv = rsv > 0.f ? 1.f / rsv : 0.f;    // pad rows sum to 0
      const int row = rowbase + mt * 16 + quad * 4 + r;
#pragma unroll
      for (int nt = 0; nt < 2; ++nt)
        ao[row * 136 + h * 32 + nt * 16 + l16] = f2bf(o[mt][nt][r] * rinv);
    }
  __syncthreads();   // (4) AO ready

  // ---- proj: rows [rowbase,+32), cols [h*32,h*32+32) ----
  f32x4 po[2][2];
#pragma unroll
  for (int mt = 0; mt < 2; ++mt)
#pragma unroll
    for (int nt = 0; nt < 2; ++nt) po[mt][nt] = fzero;
#pragma unroll
  for (int kt = 0; kt < 4; ++kt) {
    s16x8 a[2], b[2];
#pragma unroll
    for (int mt = 0; mt < 2; ++mt)
      a[mt] = *(const s16x8*)(ao + (rowbase + mt * 16 + l16) * 136 + kt * 32 + quad * 8);
#pragma unroll
    for (int nt = 0; nt < 2; ++nt)
      b[nt] = *(const s16x8*)(pT + (size_t)(h * 32 + nt * 16 + l16) * 128 + kt * 32 + quad * 8);
#pragma unroll
    for (int mt = 0; mt < 2; ++mt)
#pragma unroll
      for (int nt = 0; nt < 2; ++nt)
        po[mt][nt] = mfma_bf16(a[mt], b[nt], po[mt][nt]);
  }

  // ---- po + bias -> fp32 stage (disjoint from AO bytes) ----
#pragma unroll
  for (int nt = 0; nt < 2; ++nt) {
    const int col = h * 32 + nt * 16 + l16;
    const float pb = proj_b[col];
#pragma unroll
    for (int mt = 0; mt < 2; ++mt)
#pragma unroll
      for (int r = 0; r < 4; ++r) {
        const int row = rowbase + mt * 16 + quad * 4 + r;
        if (row < NTOK) stage[row * 132 + col] = po[mt][nt][r] + pb;
      }
  }
  __syncthreads();   // (5) stage ready

  // ---- streaming store: full 128B lines, perfect write combining ----
  float* outw = out + (size_t)w * (NTOK * CH);
  for (int t = tid; t < NTOK * 32; t += 512) {
    const int row = t >> 5;
    const int c4  = (t & 31) << 2;
    const float4 v = *(const float4*)(stage + row * 132 + c4);
    *(float4*)(outw + row * CH + c4) = v;
  }
}

extern "C" void kernel_launch(void* const* d_in, const int* in_sizes, int n_in,
                              void* d_out, int out_size, void* d_ws, size_t ws_size,
                              hipStream_t stream) {
  (void)in_sizes; (void)n_in; (void)out_size; (void)ws_size;
  const float* x          = (const float*)d_in[0];
  const float* qkv_w      = (const float*)d_in[1];
  const float* qkv_b      = (const float*)d_in[2];
  const float* proj_w     = (const float*)d_in[3];
  const float* proj_b     = (const float*)d_in[4];
  const float* bias_table = (const float*)d_in[5];
  const float* mask       = (const float*)d_in[6];
  float* out = (float*)d_out;

  unsigned short* wT = (unsigned short*)d_ws;          // 384*128 bf16
  unsigned short* pT = wT + 384 * 128;                 // 128*128 bf16
  float* rpb = (float*)(pT + 128 * 128);               // 4*49*49 f32 (@131072 B)

  const int prep_items = 384 * 128 + 128 * 128 + NHEAD * NTOK * NTOK;
  prep_kernel<<<(prep_items + 255) / 256, 256, 0, stream>>>(qkv_w, proj_w, bias_table,
                                                            wT, pT, rpb);
  attn_fused_kernel<<<4096, 512, 0, stream>>>(x, qkv_b, proj_b, mask, wT, pT, rpb, out);
}